// Round 12
// baseline (182.651 us; speedup 1.0000x reference)
//
#include <hip/hip_runtime.h>
#include <cstdint>
#include <cstddef>

#define N_NODES 50000
#define N_PAD 50048          // 782 tiles * 64 rows
#define N_EDGES 800000
#define DIM_IN 128
#define DIM_H 256
#define CAP 64
#define NBKT 391             // coarse buckets (dst>>7)
#define BCAP 2560
#define BINA_BLOCKS 400
#define EPB 2000

using u16 = unsigned short;
using u32 = unsigned int;
using u8 = unsigned char;

typedef __attribute__((ext_vector_type(8))) short bf16x8;
typedef __attribute__((ext_vector_type(4))) float f32x4;
typedef __attribute__((ext_vector_type(2))) float f32x2;

__device__ __forceinline__ u16 f2bf(float x) {
    u32 u = __float_as_uint(x);
    u32 r = (u + 0x7fffu + ((u >> 16) & 1u)) >> 16;
    return (u16)r;
}

// ---- fp8 e4m3(fn, OCP) encode/decode ----
__device__ __forceinline__ u8 enc1_sw(float f) {
    u32 u = __float_as_uint(f);
    u32 s = (u >> 24) & 0x80u;
    u32 a = u & 0x7fffffffu;
    if (a >= 0x43e00000u) return (u8)(s | 0x7e);
    if (a < 0x3c800000u) return (u8)s;
    u32 r = a + 0x7ffffu + ((a >> 20) & 1u);
    u32 e8 = (r >> 23) - 120u;
    if (e8 >= 16u) return (u8)(s | 0x7e);
    return (u8)(s | (e8 << 3) | ((r >> 20) & 7u));
}

__device__ __forceinline__ u32 enc4(float f0, float f1, float f2, float f3) {
#if __has_builtin(__builtin_amdgcn_cvt_pk_fp8_f32)
    int w = __builtin_amdgcn_cvt_pk_fp8_f32(f0, f1, 0, false);
    w = __builtin_amdgcn_cvt_pk_fp8_f32(f2, f3, w, true);
    return (u32)w;
#else
    return (u32)enc1_sw(f0) | ((u32)enc1_sw(f1) << 8) |
           ((u32)enc1_sw(f2) << 16) | ((u32)enc1_sw(f3) << 24);
#endif
}

__device__ __forceinline__ u8 enc1(float f) {
#if __has_builtin(__builtin_amdgcn_cvt_pk_fp8_f32)
    return (u8)(__builtin_amdgcn_cvt_pk_fp8_f32(f, 0.f, 0, false) & 0xff);
#else
    return enc1_sw(f);
#endif
}

__device__ __forceinline__ void dec_u32(float* o, u32 w) {
#if __has_builtin(__builtin_amdgcn_cvt_pk_f32_fp8)
    f32x2 a = __builtin_amdgcn_cvt_pk_f32_fp8(w, false);
    f32x2 b = __builtin_amdgcn_cvt_pk_f32_fp8(w, true);
    o[0] = a[0]; o[1] = a[1]; o[2] = b[0]; o[3] = b[1];
#else
    #pragma unroll
    for (int k = 0; k < 4; ++k) {
        u32 x = (w >> (8 * k)) & 0xffu;
        u32 bits = ((x & 0x80u) << 24) | ((x & 0x7fu) << 20);
        o[k] = __uint_as_float(bits) * __uint_as_float(0x7b800000u);  // *2^120
    }
#endif
}

__device__ __forceinline__ void gld_lds16(const u16* g, u16* l) {
    __builtin_amdgcn_global_load_lds(
        (__attribute__((address_space(1))) void*)g,
        (__attribute__((address_space(3))) void*)l, 16, 0, 0);
}

__device__ __forceinline__ void acc16_add(float* acc, uint4 a) {
    float t[4];
    dec_u32(t, a.x); acc[0] += t[0]; acc[1] += t[1]; acc[2] += t[2]; acc[3] += t[3];
    dec_u32(t, a.y); acc[4] += t[0]; acc[5] += t[1]; acc[6] += t[2]; acc[7] += t[3];
    dec_u32(t, a.z); acc[8] += t[0]; acc[9] += t[1]; acc[10] += t[2]; acc[11] += t[3];
    dec_u32(t, a.w); acc[12] += t[0]; acc[13] += t[1]; acc[14] += t[2]; acc[15] += t[3];
}

// ---------------- two-phase binned CSR build ----------------
__global__ __launch_bounds__(256) void binA(
    const int* __restrict__ src, const int* __restrict__ dst,
    int* __restrict__ gcur, int2* __restrict__ binbuf) {
    __shared__ int hist[NBKT];
    __shared__ int base[NBKT];
    const int tid = threadIdx.x;
    const int e0 = blockIdx.x * EPB;
    const int e1 = min(e0 + EPB, N_EDGES);
    for (int t = tid; t < NBKT; t += 256) hist[t] = 0;
    __syncthreads();
    for (int i = e0 + tid; i < e1; i += 256)
        atomicAdd(&hist[dst[i] >> 7], 1);
    __syncthreads();
    for (int t = tid; t < NBKT; t += 256) {
        int h = hist[t];
        base[t] = h ? atomicAdd(&gcur[t], h) : 0;
    }
    __syncthreads();
    for (int t = tid; t < NBKT; t += 256) hist[t] = 0;
    __syncthreads();
    for (int i = e0 + tid; i < e1; i += 256) {
        int d = dst[i];
        int b = d >> 7;
        int o = base[b] + atomicAdd(&hist[b], 1);
        if (o < (b + 1) * BCAP) binbuf[o] = make_int2(src[i], d);
    }
}

__global__ __launch_bounds__(256) void binB(
    const int* __restrict__ gcur, const int2* __restrict__ binbuf,
    int* __restrict__ cnt, int* __restrict__ csr) {
    __shared__ int lcnt[128];
    __shared__ int lcsr[128 * CAP];   // 32 KB
    const int b = blockIdx.x;
    const int tid = threadIdx.x;
    if (tid < 128) lcnt[tid] = 0;
    __syncthreads();
    int gc = gcur[b] - b * BCAP;
    if (gc > BCAP) gc = BCAP;
    for (int i = tid; i < gc; i += 256) {
        int2 p = binbuf[b * BCAP + i];
        int n = p.y & 127;
        int slot = atomicAdd(&lcnt[n], 1);
        if (slot < CAP) lcsr[n * CAP + slot] = p.x;
    }
    __syncthreads();
    const uint4* ls = reinterpret_cast<const uint4*>(lcsr);
    uint4* gs = reinterpret_cast<uint4*>(csr + (size_t)b * 128 * CAP);
    for (int i = tid; i < 128 * CAP / 4; i += 256) gs[i] = ls[i];
    if (tid < 128) {
        int v = b * 128 + tid;
        if (v < N_NODES) cnt[v] = lcnt[tid];
    }
}

// ---------------- merged prep ----------------
__global__ __launch_bounds__(256) void prep(
    const float* __restrict__ x,
    const float* __restrict__ W1_l, const float* __restrict__ W1_r,
    const float* __restrict__ W2_l, const float* __restrict__ W2_r,
    const float* __restrict__ Wh1,
    u16* __restrict__ x_hi, u32* __restrict__ x_f8,
    u16* __restrict__ w1l, u16* __restrict__ w1r,
    u16* __restrict__ w2l, u16* __restrict__ w2r, u16* __restrict__ wh1,
    int* __restrict__ gcur) {
    int b = blockIdx.x, tid = threadIdx.x;
    if (b < 2) {
        int i = b * 256 + tid;
        if (i < NBKT) gcur[i] = i * BCAP;
        return;
    }
    b -= 2;
    if (b < 6250) {
        int i = b * 256 + tid;
        float4 v = reinterpret_cast<const float4*>(x)[i];
        ushort4 h;
        h.x = f2bf(v.x); h.y = f2bf(v.y); h.z = f2bf(v.z); h.w = f2bf(v.w);
        reinterpret_cast<ushort4*>(x_hi)[i] = h;
        x_f8[i] = enc4(v.x, v.y, v.z, v.w);
        return;
    }
    b -= 6250;
    if (b < 128) {
        int idx = b * 256 + tid; int m = idx >> 7, k = idx & 127;
        w1l[idx] = f2bf(W1_l[(size_t)k * 256 + m]); return;
    }
    b -= 128;
    if (b < 128) {
        int idx = b * 256 + tid; int m = idx >> 7, k = idx & 127;
        w1r[idx] = f2bf(W1_r[(size_t)k * 256 + m]); return;
    }
    b -= 128;
    if (b < 256) {
        int idx = b * 256 + tid; int m = idx >> 8, k = idx & 255;
        w2l[idx] = f2bf(W2_l[(size_t)k * 256 + m]); return;
    }
    b -= 256;
    if (b < 256) {
        int idx = b * 256 + tid; int m = idx >> 8, k = idx & 255;
        w2r[idx] = f2bf(W2_r[(size_t)k * 256 + m]); return;
    }
    b -= 256;
    {
        int idx = b * 256 + tid; int m = idx >> 8, k = idx & 255;
        wh1[idx] = f2bf(Wh1[(size_t)k * 128 + m]);
    }
}

// ---------------- fused gather + MFMA GEMM, 64x256 tile, 8 waves ----------------
// Phase G: 8 waves x 8 nodes, fp8 gather -> mean -> bf16 aggT in LDS (XOR-swizzled).
// Main loop (dbuf): phase0 A = aggT (LDS-resident), phase1 A = A2 (staged); B staged.
// MODE 0 (conv1, K=128): epilogue -> h1 bf16+fp8 via LDS, full-line stores.
// MODE 1 (conv2, K=256): fused risk head -> out.
// LDS: staging 2x20KB [0,40960) + aggT [40960, +64*K*2). MODE0 56KB, MODE1 72KB.
template <int MODE>
__global__ __launch_bounds__(512) void gemm_fused(
    const uint4* __restrict__ tab, const int* __restrict__ cnt,
    const int* __restrict__ csr,
    const u16* __restrict__ A2, const u16* __restrict__ B0,
    const u16* __restrict__ B1, const float* __restrict__ bias,
    const u16* __restrict__ wh1t, const float* __restrict__ bh1,
    const float* __restrict__ wh2, const float* __restrict__ bh2,
    u16* __restrict__ Chi, u8* __restrict__ Cf8, float* __restrict__ outF,
    int nrows) {
    constexpr int KD = MODE ? 256 : 128;      // K per phase == agg dim
    constexpr int U4R = KD / 16;              // uint4 per fp8 row
    constexpr int EPI = 64 / U4R;             // edges gathered in parallel
    constexpr int nks = KD / 32;
    constexpr int NIT = 2 * nks;
    constexpr int AGG_OFF = 40960;            // bytes
    __shared__ __align__(16) u16 SMEM[(40960 + 64 * KD * 2) / 2];

    const int tid = threadIdx.x;
    const int lane = tid & 63;
    const int w = tid >> 6;
    const int wr = w >> 2, wc = w & 3;        // wave grid 2x4 over 64x256
    const int row0 = blockIdx.x * 64;

    const int srow = lane >> 2;
    const int swz = (((lane & 3) ^ (srow & 3)) * 8);

    // ---- Phase G: gather 64 nodes (8 per wave) into aggT ----
    {
        const int q = lane & (U4R - 1);
        const int e = lane / U4R;
        char* aggb = (char*)SMEM + AGG_OFF;
        for (int n = 0; n < 8; ++n) {
            int lrow = w * 8 + n;
            int v = row0 + lrow;
            int d = (v < N_NODES) ? cnt[v] : 0;
            int dl = min(d, CAP);
            int myidx = (lane < dl) ? csr[v * CAP + lane] : 0;
            float acc[16] = {};
            int j = 0;
            for (; j + 2 * EPI <= dl; j += 2 * EPI) {
                int i0 = __shfl(myidx, j + e, 64);
                int i1 = __shfl(myidx, j + EPI + e, 64);
                uint4 a = tab[(size_t)i0 * U4R + q];
                uint4 b = tab[(size_t)i1 * U4R + q];
                acc16_add(acc, a);
                acc16_add(acc, b);
            }
            for (; j + EPI <= dl; j += EPI) {
                int i0 = __shfl(myidx, j + e, 64);
                uint4 a = tab[(size_t)i0 * U4R + q];
                acc16_add(acc, a);
            }
            int r = dl - j;
            if (r > 0) {
                int ee = (e < r) ? e : 0;
                int i0 = __shfl(myidx, j + ee, 64);
                uint4 a = tab[(size_t)i0 * U4R + q];
                if (e < r) acc16_add(acc, a);
            }
            #pragma unroll
            for (int s = U4R; s < 64; s <<= 1)
                #pragma unroll
                for (int i = 0; i < 16; ++i) acc[i] += __shfl_xor(acc[i], s, 64);
            const float inv = 1.f / (float)((d > 0) ? d : 1);
            if (e == 0) {
                u32 wd[8];
                #pragma unroll
                for (int k = 0; k < 8; ++k) {
                    float m0 = acc[2 * k] * inv, m1 = acc[2 * k + 1] * inv;
                    wd[k] = ((u32)f2bf(m1) << 16) | f2bf(m0);
                }
                char* rowp = aggb + (size_t)lrow * (KD * 2);
                int sw = (lrow & 7) << 4;
                *(uint4*)(rowp + ((q * 32) ^ sw)) = *(uint4*)&wd[0];
                *(uint4*)(rowp + ((q * 32 + 16) ^ sw)) = *(uint4*)&wd[4];
            }
        }
    }

    f32x4 zero4 = {0.f, 0.f, 0.f, 0.f};
    f32x4 acc[2][4];
    #pragma unroll
    for (int i = 0; i < 2; ++i)
        #pragma unroll
        for (int j = 0; j < 4; ++j) acc[i][j] = zero4;

    auto stage = [&](int it, int buf) {
        const int ph = (it >= nks) ? 1 : 0;
        const int kk = it - ph * nks;
        char* base = (char*)SMEM + buf * 20480;
        if (ph == 0) {
            #pragma unroll
            for (int t = 0; t < 2; ++t) {
                int s = w * 2 + t;                       // 16 B slabs
                int gcol = s * 16 + srow;
                gld_lds16(B0 + (size_t)gcol * KD + kk * 32 + swz,
                          (u16*)(base + 4096 + s * 1024));
            }
        } else {
            #pragma unroll
            for (int t = 0; t < 3; ++t) {
                int s = w * 3 + t;
                if (s >= 20) continue;
                if (s < 4) {                             // A2 slabs (64 rows)
                    int grow = row0 + s * 16 + srow;
                    if (grow > nrows - 1) grow = nrows - 1;
                    gld_lds16(A2 + (size_t)grow * KD + kk * 32 + swz,
                              (u16*)(base + s * 1024));
                } else {                                 // B1 slabs
                    int gcol = (s - 4) * 16 + srow;
                    gld_lds16(B1 + (size_t)gcol * KD + kk * 32 + swz,
                              (u16*)(base + 4096 + (s - 4) * 1024));
                }
            }
        }
    };

    stage(0, 0);
    __syncthreads();     // aggT written + stage0 landed
    for (int it = 0; it < NIT; ++it) {
        if (it + 1 < NIT) stage(it + 1, (it + 1) & 1);
        const int ph = (it >= nks) ? 1 : 0;
        const char* base_ = (const char*)SMEM + (it & 1) * 20480;
        bf16x8 af[2], bfr[4];
        if (ph == 0) {
            const char* aggb = (const char*)SMEM + AGG_OFF;
            const int kit = it;
            #pragma unroll
            for (int i = 0; i < 2; ++i) {
                int tr = wr * 32 + i * 16 + (lane & 15);
                af[i] = *reinterpret_cast<const bf16x8*>(
                    aggb + (size_t)tr * (KD * 2) +
                    ((kit * 64 + (lane >> 4) * 16) ^ ((tr & 7) << 4)));
            }
        } else {
            #pragma unroll
            for (int i = 0; i < 2; ++i) {
                int tr = wr * 32 + i * 16 + (lane & 15);
                af[i] = *reinterpret_cast<const bf16x8*>(
                    base_ + tr * 64 + (((lane >> 4) ^ (tr & 3)) * 16));
            }
        }
        #pragma unroll
        for (int j = 0; j < 4; ++j) {
            int tc = wc * 64 + j * 16 + (lane & 15);
            bfr[j] = *reinterpret_cast<const bf16x8*>(
                base_ + 4096 + tc * 64 + (((lane >> 4) ^ (tc & 3)) * 16));
        }
        #pragma unroll
        for (int i = 0; i < 2; ++i)
            #pragma unroll
            for (int j = 0; j < 4; ++j)
                acc[i][j] = __builtin_amdgcn_mfma_f32_16x16x32_bf16(
                    af[i], bfr[j], acc[i][j], 0, 0, 0);
        __syncthreads();
    }

    if (MODE == 0) {
        // ---- epilogue: h1 tile (bf16 + fp8) via LDS, full-line stores ----
        u16* hL = SMEM;                       // [64][256] bf16, 32KB
        u8* fL = (u8*)SMEM + 32768;           // [64][256] fp8, 16KB
        #pragma unroll
        for (int i = 0; i < 2; ++i)
            #pragma unroll
            for (int j = 0; j < 4; ++j) {
                int col = wc * 64 + j * 16 + (lane & 15);
                float b = bias[col];
                #pragma unroll
                for (int r = 0; r < 4; ++r) {
                    int row = wr * 32 + i * 16 + (lane >> 4) * 4 + r;
                    float v = fmaxf(acc[i][j][r] + b, 0.f);
                    hL[row * 256 + col] = f2bf(v);
                    fL[row * 256 + col] = enc1(v);
                }
            }
        __syncthreads();
        uint4* gh = reinterpret_cast<uint4*>(Chi + (size_t)row0 * 256);
        const uint4* lh = reinterpret_cast<const uint4*>(hL);
        #pragma unroll
        for (int k2 = 0; k2 < 4; ++k2) gh[tid + k2 * 512] = lh[tid + k2 * 512];
        uint4* gf = reinterpret_cast<uint4*>(Cf8 + (size_t)row0 * 256);
        const uint4* lf = reinterpret_cast<const uint4*>(fL);
        #pragma unroll
        for (int k2 = 0; k2 < 2; ++k2) gf[tid + k2 * 512] = lf[tid + k2 * 512];
    } else {
        // ---- fused risk head ----
        u16* Bs2 = SMEM + 16384;                // byte 32768, 8KB (staging dead)
        float* hpart = (float*)((char*)SMEM + AGG_OFF);  // [4][64], aggT dead
        {
            int gcol = w * 16 + srow;
            gld_lds16(wh1t + (size_t)gcol * 256 + 0 * 32 + swz, Bs2 + w * 512);
        }
        char* hb = (char*)SMEM;                 // h2 tile [64][512B], swizzled
        #pragma unroll
        for (int i = 0; i < 2; ++i)
            #pragma unroll
            for (int j = 0; j < 4; ++j) {
                int col = wc * 64 + j * 16 + (lane & 15);
                float b = bias[col];
                #pragma unroll
                for (int r = 0; r < 4; ++r) {
                    int row = wr * 32 + i * 16 + (lane >> 4) * 4 + r;
                    float v = fmaxf(acc[i][j][r] + b, 0.f);
                    int byt = row * 512 + col * 2;
                    *(u16*)(hb + (byt ^ ((row & 7) << 4))) = f2bf(v);
                }
            }
        __syncthreads();

        // head GEMM: [64 rows]x[128 cols], K=256, A from LDS h2, single-buf B
        f32x4 acc2[2][2];
        #pragma unroll
        for (int i = 0; i < 2; ++i) { acc2[i][0] = zero4; acc2[i][1] = zero4; }
        for (int kk = 0; kk < 8; ++kk) {
            const char* B2 = (const char*)Bs2;
            bf16x8 af2[2], bfr2[2];
            #pragma unroll
            for (int i = 0; i < 2; ++i) {
                int row = wr * 32 + i * 16 + (lane & 15);
                int byt = row * 512 + kk * 64 + (lane >> 4) * 16;
                af2[i] = *reinterpret_cast<const bf16x8*>(hb + (byt ^ ((row & 7) << 4)));
            }
            #pragma unroll
            for (int j = 0; j < 2; ++j) {
                int tc = wc * 32 + j * 16 + (lane & 15);
                bfr2[j] = *reinterpret_cast<const bf16x8*>(
                    B2 + tc * 64 + (((lane >> 4) ^ (tc & 3)) * 16));
            }
            __syncthreads();                     // all waves done reading Bs2
            if (kk + 1 < 8) {
                int gcol = w * 16 + srow;
                gld_lds16(wh1t + (size_t)gcol * 256 + (kk + 1) * 32 + swz,
                          Bs2 + w * 512);
            }
            #pragma unroll
            for (int i = 0; i < 2; ++i)
                #pragma unroll
                for (int j = 0; j < 2; ++j)
                    acc2[i][j] = __builtin_amdgcn_mfma_f32_16x16x32_bf16(
                        af2[i], bfr2[j], acc2[i][j], 0, 0, 0);
            __syncthreads();
        }

        // relu + dot(wh2) + sigmoid
        float pr[2][4];
        #pragma unroll
        for (int i = 0; i < 2; ++i)
            #pragma unroll
            for (int r = 0; r < 4; ++r) pr[i][r] = 0.f;
        #pragma unroll
        for (int j = 0; j < 2; ++j) {
            int col = wc * 32 + j * 16 + (lane & 15);
            float b1 = bh1[col];
            float wv = wh2[col];
            #pragma unroll
            for (int i = 0; i < 2; ++i)
                #pragma unroll
                for (int r = 0; r < 4; ++r)
                    pr[i][r] += fmaxf(acc2[i][j][r] + b1, 0.f) * wv;
        }
        #pragma unroll
        for (int i = 0; i < 2; ++i)
            #pragma unroll
            for (int r = 0; r < 4; ++r) {
                float s = pr[i][r];
                s += __shfl_xor(s, 1, 64);
                s += __shfl_xor(s, 2, 64);
                s += __shfl_xor(s, 4, 64);
                s += __shfl_xor(s, 8, 64);
                pr[i][r] = s;
            }
        if ((lane & 15) == 0) {
            #pragma unroll
            for (int i = 0; i < 2; ++i)
                #pragma unroll
                for (int r = 0; r < 4; ++r)
                    hpart[wc * 64 + wr * 32 + i * 16 + (lane >> 4) * 4 + r] = pr[i][r];
        }
        __syncthreads();
        if (tid < 64) {
            int row = row0 + tid;
            if (row < nrows) {
                float s = hpart[tid] + hpart[64 + tid] + hpart[128 + tid]
                        + hpart[192 + tid] + bh2[0];
                outF[row] = 1.f / (1.f + expf(-s));
            }
        }
    }
}

static inline size_t align256(size_t x) { return (x + 255) & ~(size_t)255; }

extern "C" void kernel_launch(void* const* d_in, const int* in_sizes, int n_in,
                              void* d_out, int out_size, void* d_ws, size_t ws_size,
                              hipStream_t stream) {
    const float* x    = (const float*)d_in[0];
    const int* ei     = (const int*)d_in[1];
    const float* W1_l = (const float*)d_in[2];
    const float* b1_l = (const float*)d_in[3];
    const float* W1_r = (const float*)d_in[4];
    const float* W2_l = (const float*)d_in[5];
    const float* b2_l = (const float*)d_in[6];
    const float* W2_r = (const float*)d_in[7];
    const float* Wh1  = (const float*)d_in[8];
    const float* bh1  = (const float*)d_in[9];
    const float* Wh2  = (const float*)d_in[10];
    const float* bh2  = (const float*)d_in[11];
    float* out = (float*)d_out;

    const int* src = ei;
    const int* dst = ei + N_EDGES;

    const size_t SZ_N128 = (size_t)N_NODES * DIM_IN * sizeof(u16);   // 12.8 MB
    const size_t SZ_W128x256 = (size_t)128 * 256 * sizeof(u16);      // 64 KB

    char* ws = (char*)d_ws;
    size_t off_ = 0;
    auto alloc = [&](size_t bytes) { size_t o = off_; off_ += align256(bytes); return o; };

    size_t o_cnt = alloc((size_t)N_PAD * 4);
    size_t o_gcur = alloc((size_t)512 * 4);
    size_t o_csr = alloc((size_t)N_PAD * CAP * 4);           // 12.8 MB
    size_t o_bin = alloc((size_t)NBKT * BCAP * 8);           // 8 MB
    size_t o_w1l = alloc(SZ_W128x256);
    size_t o_w1r = alloc(SZ_W128x256);
    size_t o_w2l = alloc(2 * SZ_W128x256);
    size_t o_w2r = alloc(2 * SZ_W128x256);
    size_t o_wh1 = alloc(SZ_W128x256);
    size_t o_xh  = alloc(SZ_N128);
    size_t o_xf8 = alloc((size_t)N_NODES * DIM_IN);          // 6.4 MB fp8
    size_t o_h1  = alloc((size_t)N_PAD * DIM_H * sizeof(u16));  // padded rows
    size_t o_h1f = alloc((size_t)N_PAD * DIM_H);                // padded rows
    if (ws_size < off_) return;

    int* cnt  = (int*)(ws + o_cnt);
    int* gcur = (int*)(ws + o_gcur);
    int* csr  = (int*)(ws + o_csr);
    int2* binbuf = (int2*)(ws + o_bin);
    u16* w1l_h = (u16*)(ws + o_w1l);
    u16* w1r_h = (u16*)(ws + o_w1r);
    u16* w2l_h = (u16*)(ws + o_w2l);
    u16* w2r_h = (u16*)(ws + o_w2r);
    u16* wh1_h = (u16*)(ws + o_wh1);
    u16* x_hi    = (u16*)(ws + o_xh);
    u32* x_f8    = (u32*)(ws + o_xf8);
    u16* h1_hi   = (u16*)(ws + o_h1);
    u8*  h1_f8   = (u8*)(ws + o_h1f);

    // ---- prep: gcur init + x (bf16+fp8) + weight transposes, 1 launch ----
    prep<<<2 + 6250 + 128 + 128 + 256 + 256 + 128, 256, 0, stream>>>(
        x, W1_l, W1_r, W2_l, W2_r, Wh1,
        x_hi, x_f8, w1l_h, w1r_h, w2l_h, w2r_h, wh1_h, gcur);

    // ---- two-phase binned CSR ----
    binA<<<BINA_BLOCKS, 256, 0, stream>>>(src, dst, gcur, binbuf);
    binB<<<NBKT, 256, 0, stream>>>(gcur, binbuf, cnt, csr);

    const int RB = N_PAD / 64;   // 782 row blocks

    // ---- conv1: fused gather(x_f8) + GEMM -> h1 (bf16 + fp8) ----
    gemm_fused<0><<<RB, 512, 0, stream>>>(
        (const uint4*)x_f8, cnt, csr, x_hi, w1l_h, w1r_h, b1_l,
        nullptr, nullptr, nullptr, nullptr, h1_hi, h1_f8, nullptr, N_NODES);

    // ---- conv2: fused gather(h1_f8) + GEMM + risk head -> out ----
    gemm_fused<1><<<RB, 512, 0, stream>>>(
        (const uint4*)h1_f8, cnt, csr, h1_hi, w2l_h, w2r_h, b2_l,
        wh1_h, bh1, Wh2, bh2, nullptr, nullptr, out, N_NODES);
}

// Round 13
// 146.826 us; speedup vs baseline: 1.2440x; 1.2440x over previous
//
#include <hip/hip_runtime.h>
#include <cstdint>
#include <cstddef>

#define N_NODES 50000
#define N_PAD 50048          // 391 tiles * 128 rows
#define N_EDGES 800000
#define DIM_IN 128
#define DIM_H 256
#define CAP 64
#define NBKT 391             // coarse buckets (dst>>7)
#define BCAP 2560
#define BINA_BLOCKS 400
#define EPB 2000

using u16 = unsigned short;
using u32 = unsigned int;
using u8 = unsigned char;

typedef __attribute__((ext_vector_type(8))) short bf16x8;
typedef __attribute__((ext_vector_type(4))) float f32x4;
typedef __attribute__((ext_vector_type(2))) float f32x2;

__device__ __forceinline__ u16 f2bf(float x) {
    u32 u = __float_as_uint(x);
    u32 r = (u + 0x7fffu + ((u >> 16) & 1u)) >> 16;
    return (u16)r;
}

// ---- fp8 e4m3(fn, OCP) encode/decode ----
__device__ __forceinline__ u8 enc1_sw(float f) {
    u32 u = __float_as_uint(f);
    u32 s = (u >> 24) & 0x80u;
    u32 a = u & 0x7fffffffu;
    if (a >= 0x43e00000u) return (u8)(s | 0x7e);
    if (a < 0x3c800000u) return (u8)s;
    u32 r = a + 0x7ffffu + ((a >> 20) & 1u);
    u32 e8 = (r >> 23) - 120u;
    if (e8 >= 16u) return (u8)(s | 0x7e);
    return (u8)(s | (e8 << 3) | ((r >> 20) & 7u));
}

__device__ __forceinline__ u32 enc4(float f0, float f1, float f2, float f3) {
#if __has_builtin(__builtin_amdgcn_cvt_pk_fp8_f32)
    int w = __builtin_amdgcn_cvt_pk_fp8_f32(f0, f1, 0, false);
    w = __builtin_amdgcn_cvt_pk_fp8_f32(f2, f3, w, true);
    return (u32)w;
#else
    return (u32)enc1_sw(f0) | ((u32)enc1_sw(f1) << 8) |
           ((u32)enc1_sw(f2) << 16) | ((u32)enc1_sw(f3) << 24);
#endif
}

__device__ __forceinline__ u8 enc1(float f) {
#if __has_builtin(__builtin_amdgcn_cvt_pk_fp8_f32)
    return (u8)(__builtin_amdgcn_cvt_pk_fp8_f32(f, 0.f, 0, false) & 0xff);
#else
    return enc1_sw(f);
#endif
}

__device__ __forceinline__ void dec_u32(float* o, u32 w) {
#if __has_builtin(__builtin_amdgcn_cvt_pk_f32_fp8)
    f32x2 a = __builtin_amdgcn_cvt_pk_f32_fp8(w, false);
    f32x2 b = __builtin_amdgcn_cvt_pk_f32_fp8(w, true);
    o[0] = a[0]; o[1] = a[1]; o[2] = b[0]; o[3] = b[1];
#else
    #pragma unroll
    for (int k = 0; k < 4; ++k) {
        u32 x = (w >> (8 * k)) & 0xffu;
        u32 bits = ((x & 0x80u) << 24) | ((x & 0x7fu) << 20);
        o[k] = __uint_as_float(bits) * __uint_as_float(0x7b800000u);  // *2^120
    }
#endif
}

__device__ __forceinline__ void gld_lds16(const u16* g, u16* l) {
    __builtin_amdgcn_global_load_lds(
        (__attribute__((address_space(1))) void*)g,
        (__attribute__((address_space(3))) void*)l, 16, 0, 0);
}

// ---------------- two-phase binned CSR build ----------------
__global__ __launch_bounds__(256) void binA(
    const int* __restrict__ src, const int* __restrict__ dst,
    int* __restrict__ gcur, int2* __restrict__ binbuf) {
    __shared__ int hist[NBKT];
    __shared__ int base[NBKT];
    const int tid = threadIdx.x;
    const int e0 = blockIdx.x * EPB;
    const int e1 = min(e0 + EPB, N_EDGES);
    for (int t = tid; t < NBKT; t += 256) hist[t] = 0;
    __syncthreads();
    for (int i = e0 + tid; i < e1; i += 256)
        atomicAdd(&hist[dst[i] >> 7], 1);
    __syncthreads();
    for (int t = tid; t < NBKT; t += 256) {
        int h = hist[t];
        base[t] = h ? atomicAdd(&gcur[t], h) : 0;
    }
    __syncthreads();
    for (int t = tid; t < NBKT; t += 256) hist[t] = 0;
    __syncthreads();
    for (int i = e0 + tid; i < e1; i += 256) {
        int d = dst[i];
        int b = d >> 7;
        int o = base[b] + atomicAdd(&hist[b], 1);
        if (o < (b + 1) * BCAP) binbuf[o] = make_int2(src[i], d);
    }
}

__global__ __launch_bounds__(256) void binB(
    const int* __restrict__ gcur, const int2* __restrict__ binbuf,
    int* __restrict__ cnt, int* __restrict__ csr) {
    __shared__ int lcnt[128];
    __shared__ int lcsr[128 * CAP];   // 32 KB
    const int b = blockIdx.x;
    const int tid = threadIdx.x;
    if (tid < 128) lcnt[tid] = 0;
    __syncthreads();
    int gc = gcur[b] - b * BCAP;
    if (gc > BCAP) gc = BCAP;
    for (int i = tid; i < gc; i += 256) {
        int2 p = binbuf[b * BCAP + i];
        int n = p.y & 127;
        int slot = atomicAdd(&lcnt[n], 1);
        if (slot < CAP) lcsr[n * CAP + slot] = p.x;
    }
    __syncthreads();
    const uint4* ls = reinterpret_cast<const uint4*>(lcsr);
    uint4* gs = reinterpret_cast<uint4*>(csr + (size_t)b * 128 * CAP);
    for (int i = tid; i < 128 * CAP / 4; i += 256) gs[i] = ls[i];
    if (tid < 128) {
        int v = b * 128 + tid;
        if (v < N_NODES) cnt[v] = lcnt[tid];
    }
}

// ---------------- merged prep ----------------
__global__ __launch_bounds__(256) void prep(
    const float* __restrict__ x,
    const float* __restrict__ W1_l, const float* __restrict__ W1_r,
    const float* __restrict__ W2_l, const float* __restrict__ W2_r,
    const float* __restrict__ Wh1,
    u16* __restrict__ x_hi, u32* __restrict__ x_f8,
    u16* __restrict__ w1l, u16* __restrict__ w1r,
    u16* __restrict__ w2l, u16* __restrict__ w2r, u16* __restrict__ wh1,
    int* __restrict__ gcur) {
    int b = blockIdx.x, tid = threadIdx.x;
    if (b < 2) {
        int i = b * 256 + tid;
        if (i < NBKT) gcur[i] = i * BCAP;
        return;
    }
    b -= 2;
    if (b < 6250) {
        int i = b * 256 + tid;
        float4 v = reinterpret_cast<const float4*>(x)[i];
        ushort4 h;
        h.x = f2bf(v.x); h.y = f2bf(v.y); h.z = f2bf(v.z); h.w = f2bf(v.w);
        reinterpret_cast<ushort4*>(x_hi)[i] = h;
        x_f8[i] = enc4(v.x, v.y, v.z, v.w);
        return;
    }
    b -= 6250;
    if (b < 128) {
        int idx = b * 256 + tid; int m = idx >> 7, k = idx & 127;
        w1l[idx] = f2bf(W1_l[(size_t)k * 256 + m]); return;
    }
    b -= 128;
    if (b < 128) {
        int idx = b * 256 + tid; int m = idx >> 7, k = idx & 127;
        w1r[idx] = f2bf(W1_r[(size_t)k * 256 + m]); return;
    }
    b -= 128;
    if (b < 256) {
        int idx = b * 256 + tid; int m = idx >> 8, k = idx & 255;
        w2l[idx] = f2bf(W2_l[(size_t)k * 256 + m]); return;
    }
    b -= 256;
    if (b < 256) {
        int idx = b * 256 + tid; int m = idx >> 8, k = idx & 255;
        w2r[idx] = f2bf(W2_r[(size_t)k * 256 + m]); return;
    }
    b -= 256;
    {
        int idx = b * 256 + tid; int m = idx >> 8, k = idx & 255;
        wh1[idx] = f2bf(Wh1[(size_t)k * 128 + m]);
    }
}

// ---------------- aggregation: fp8 gather, 4 nodes/block, 1 wave each ----------------
__device__ __forceinline__ void acc16_add(float* acc, uint4 a) {
    float t[4];
    dec_u32(t, a.x); acc[0] += t[0]; acc[1] += t[1]; acc[2] += t[2]; acc[3] += t[3];
    dec_u32(t, a.y); acc[4] += t[0]; acc[5] += t[1]; acc[6] += t[2]; acc[7] += t[3];
    dec_u32(t, a.z); acc[8] += t[0]; acc[9] += t[1]; acc[10] += t[2]; acc[11] += t[3];
    dec_u32(t, a.w); acc[12] += t[0]; acc[13] += t[1]; acc[14] += t[2]; acc[15] += t[3];
}

template <int U4ROW>
__global__ __launch_bounds__(256) void aggregate_f8(
    const uint4* __restrict__ tab, const int* __restrict__ cnt,
    const int* __restrict__ csr, u16* __restrict__ out_hi, int n_nodes) {
    constexpr int EPI = 64 / U4ROW;
    constexpr int D = U4ROW * 16;
    const int lane = threadIdx.x & 63;
    const int v = blockIdx.x * 4 + (threadIdx.x >> 6);
    if (v >= n_nodes) return;
    const int q = lane & (U4ROW - 1);
    const int e = lane / U4ROW;
    const int d = cnt[v];
    const int dl = min(d, CAP);
    const int myidx = (lane < dl) ? csr[v * CAP + lane] : 0;
    float acc[16] = {};
    int j = 0;
    for (; j + 2 * EPI <= dl; j += 2 * EPI) {
        int i0 = __shfl(myidx, j + e, 64);
        int i1 = __shfl(myidx, j + EPI + e, 64);
        uint4 a = tab[(size_t)i0 * U4ROW + q];
        uint4 b = tab[(size_t)i1 * U4ROW + q];
        acc16_add(acc, a);
        acc16_add(acc, b);
    }
    for (; j + EPI <= dl; j += EPI) {
        int i0 = __shfl(myidx, j + e, 64);
        uint4 a = tab[(size_t)i0 * U4ROW + q];
        acc16_add(acc, a);
    }
    int r = dl - j;
    if (r > 0) {
        int ee = (e < r) ? e : 0;
        int i0 = __shfl(myidx, j + ee, 64);
        uint4 a = tab[(size_t)i0 * U4ROW + q];
        if (e < r) acc16_add(acc, a);
    }
    #pragma unroll
    for (int s = U4ROW; s < 64; s <<= 1)
        #pragma unroll
        for (int i = 0; i < 16; ++i) acc[i] += __shfl_xor(acc[i], s, 64);
    const float inv = 1.f / (float)((d > 0) ? d : 1);
    if (e == 0) {
        u32 w[8];
        #pragma unroll
        for (int k = 0; k < 8; ++k) {
            float m0 = acc[2 * k] * inv, m1 = acc[2 * k + 1] * inv;
            w[k] = ((u32)f2bf(m1) << 16) | f2bf(m0);
        }
        u16* dp = out_hi + (size_t)v * D + q * 16;
        *reinterpret_cast<uint4*>(dp) = *reinterpret_cast<uint4*>(&w[0]);
        *reinterpret_cast<uint4*>(dp + 8) = *reinterpret_cast<uint4*>(&w[4]);
    }
}

// ---------------- MFMA GEMM, 128x256 tile, 8 waves, double-buffered ----------------
// LDS per buf: As [128 rows][64B] 8KB + Bs [256 rows][64B] 16KB = 24KB (12288 u16).
// Chunk-XOR swizzle: (row, chunkpos) holds global chunk (chunkpos ^ (row&3)).
// MODE 0: epilogue stages C tile (bf16+fp8) through LDS, flat uint4 stores. 49152 B.
// MODE 1: fused risk head; LDS capped at 75776 B so 2 blocks/CU stay resident.
template <int MODE>
__global__ __launch_bounds__(512) void gemm_fused(
    const u16* __restrict__ Ah1, const u16* __restrict__ Ah2,
    const u16* __restrict__ Bh1, const u16* __restrict__ Bh2,
    const float* __restrict__ bias,
    const u16* __restrict__ wh1t, const float* __restrict__ bh1,
    const float* __restrict__ wh2, const float* __restrict__ bh2,
    u16* __restrict__ Chi, u8* __restrict__ Cf8, float* __restrict__ outF,
    int nrows, int K) {
    // MODE0: 49152 B = 2x24KB dbuf; epilogue reuse: hL 32KB + fL 16KB.
    // MODE1: dbuf [0,49152); epilogue: hb [0,65536); Bs2 [65536,73728); hpart [73728,75776).
    __shared__ __align__(16) u16 SMEM[(MODE == 1) ? 37888 : 24576];

    const int tid = threadIdx.x;
    const int lane = tid & 63;
    const int w = tid >> 6;
    const int wr = w >> 2, wc = w & 3;
    const int row0 = blockIdx.x * 128;

    f32x4 zero4 = {0.f, 0.f, 0.f, 0.f};
    f32x4 acc[4][4];
    #pragma unroll
    for (int i = 0; i < 4; ++i)
        #pragma unroll
        for (int j = 0; j < 4; ++j) acc[i][j] = zero4;

    const int srow = lane >> 2;                          // row within 16-row slab
    const int swz = (((lane & 3) ^ (srow & 3)) * 8);     // swizzled k-chunk (elems)

    const int nks = K >> 5;
    const int NIT = 2 * nks;

    auto stage = [&](int it, int buf) {
        const int ph = (it >= nks) ? 1 : 0;
        const int kk = it - ph * nks;
        const u16* Ab = ph ? Ah2 : Ah1;
        const u16* Bb = ph ? Bh2 : Bh1;
        u16* base = SMEM + buf * 12288;
        #pragma unroll
        for (int t = 0; t < 3; ++t) {
            int slab = w * 3 + t;
            if (slab < 8) {
                int grow = row0 + slab * 16 + srow;
                if (grow > nrows - 1) grow = nrows - 1;
                gld_lds16(Ab + (size_t)grow * K + kk * 32 + swz, base + slab * 512);
            } else {
                int gcol = (slab - 8) * 16 + srow;
                gld_lds16(Bb + (size_t)gcol * K + kk * 32 + swz,
                          base + 4096 + (slab - 8) * 512);
            }
        }
    };

    stage(0, 0);
    __syncthreads();
    int cur = 0;
    for (int it = 0; it < NIT; ++it) {
        if (it + 1 < NIT) stage(it + 1, cur ^ 1);
        const char* As_ = (const char*)(SMEM + cur * 12288);
        const char* Bs_ = As_ + 8192;
        bf16x8 af[4], bfr[4];
        #pragma unroll
        for (int i = 0; i < 4; ++i) {
            int tr = wr * 64 + i * 16 + (lane & 15);
            af[i] = *reinterpret_cast<const bf16x8*>(
                As_ + tr * 64 + (((lane >> 4) ^ (tr & 3)) * 16));
        }
        #pragma unroll
        for (int j = 0; j < 4; ++j) {
            int tc = wc * 64 + j * 16 + (lane & 15);
            bfr[j] = *reinterpret_cast<const bf16x8*>(
                Bs_ + tc * 64 + (((lane >> 4) ^ (tc & 3)) * 16));
        }
        #pragma unroll
        for (int i = 0; i < 4; ++i)
            #pragma unroll
            for (int j = 0; j < 4; ++j)
                acc[i][j] = __builtin_amdgcn_mfma_f32_16x16x32_bf16(
                    af[i], bfr[j], acc[i][j], 0, 0, 0);
        __syncthreads();
        cur ^= 1;
    }

    if (MODE == 0) {
        // ---- epilogue through LDS: full-line packed stores (rows padded to N_PAD) ----
        u16* hL = SMEM;                       // [64][256] bf16, 32KB
        u8* fL = (u8*)SMEM + 32768;           // [64][256] fp8, 16KB
        #pragma unroll
        for (int half = 0; half < 2; ++half) {
            if (wr == half) {
                #pragma unroll
                for (int i = 0; i < 4; ++i)
                    #pragma unroll
                    for (int j = 0; j < 4; ++j) {
                        int col = wc * 64 + j * 16 + (lane & 15);
                        float b = bias[col];
                        #pragma unroll
                        for (int r = 0; r < 4; ++r) {
                            int rl = i * 16 + (lane >> 4) * 4 + r;   // 0..63
                            float v = fmaxf(acc[i][j][r] + b, 0.f);
                            hL[rl * 256 + col] = f2bf(v);
                            fL[rl * 256 + col] = enc1(v);
                        }
                    }
            }
            __syncthreads();
            size_t gr0 = (size_t)(row0 + half * 64);
            uint4* gh = reinterpret_cast<uint4*>(Chi + gr0 * 256);
            const uint4* lh = reinterpret_cast<const uint4*>(hL);
            #pragma unroll
            for (int k2 = 0; k2 < 4; ++k2) gh[tid + k2 * 512] = lh[tid + k2 * 512];
            uint4* gf = reinterpret_cast<uint4*>(Cf8 + gr0 * 256);
            const uint4* lf = reinterpret_cast<const uint4*>(fL);
            #pragma unroll
            for (int k2 = 0; k2 < 2; ++k2) gf[tid + k2 * 512] = lf[tid + k2 * 512];
            __syncthreads();
        }
    } else {
        // ---- stage head B slab 0 early; write relu'd h2 tile to LDS ----
        u16* Bs2 = SMEM + 32768;                // byte 65536, single 8KB buffer
        float* hpart = (float*)(SMEM + 36864);  // byte 73728, [4][128]
        {
            int gcol = w * 16 + srow;
            gld_lds16(wh1t + (size_t)gcol * 256 + 0 * 32 + swz, Bs2 + w * 512);
        }
        char* hb = (char*)SMEM;
        #pragma unroll
        for (int i = 0; i < 4; ++i)
            #pragma unroll
            for (int j = 0; j < 4; ++j) {
                int col = wc * 64 + j * 16 + (lane & 15);
                float b = bias[col];
                #pragma unroll
                for (int r = 0; r < 4; ++r) {
                    int row = wr * 64 + i * 16 + (lane >> 4) * 4 + r;
                    float v = fmaxf(acc[i][j][r] + b, 0.f);
                    int byt = row * 512 + col * 2;
                    *(u16*)(hb + (byt ^ ((row & 7) << 4))) = f2bf(v);
                }
            }
        __syncthreads();

        // ---- head GEMM: [128 rows]x[128 cols], K=256, A from LDS h2, single-buf B ----
        const int whr = wr, whc = wc;
        f32x4 acc2[4][2];
        #pragma unroll
        for (int i = 0; i < 4; ++i) { acc2[i][0] = zero4; acc2[i][1] = zero4; }
        for (int kk = 0; kk < 8; ++kk) {
            const char* B2 = (const char*)Bs2;
            bf16x8 af2[4], bfr2[2];
            #pragma unroll
            for (int i = 0; i < 4; ++i) {
                int row = whr * 64 + i * 16 + (lane & 15);
                int byt = row * 512 + kk * 64 + (lane >> 4) * 16;
                af2[i] = *reinterpret_cast<const bf16x8*>(hb + (byt ^ ((row & 7) << 4)));
            }
            #pragma unroll
            for (int j = 0; j < 2; ++j) {
                int tc = whc * 32 + j * 16 + (lane & 15);
                bfr2[j] = *reinterpret_cast<const bf16x8*>(
                    B2 + tc * 64 + (((lane >> 4) ^ (tc & 3)) * 16));
            }
            __syncthreads();                     // all waves done reading Bs2
            if (kk + 1 < 8) {                    // overwrite under MFMA
                int gcol = w * 16 + srow;
                gld_lds16(wh1t + (size_t)gcol * 256 + (kk + 1) * 32 + swz,
                          Bs2 + w * 512);
            }
            #pragma unroll
            for (int i = 0; i < 4; ++i)
                #pragma unroll
                for (int j = 0; j < 2; ++j)
                    acc2[i][j] = __builtin_amdgcn_mfma_f32_16x16x32_bf16(
                        af2[i], bfr2[j], acc2[i][j], 0, 0, 0);
            __syncthreads();                     // staging drained (vmcnt at barrier)
        }

        // ---- relu + dot(wh2) + sigmoid ----
        float pr[4][4];
        #pragma unroll
        for (int i = 0; i < 4; ++i)
            #pragma unroll
            for (int r = 0; r < 4; ++r) pr[i][r] = 0.f;
        #pragma unroll
        for (int j = 0; j < 2; ++j) {
            int col = whc * 32 + j * 16 + (lane & 15);
            float b1 = bh1[col];
            float wv = wh2[col];
            #pragma unroll
            for (int i = 0; i < 4; ++i)
                #pragma unroll
                for (int r = 0; r < 4; ++r)
                    pr[i][r] += fmaxf(acc2[i][j][r] + b1, 0.f) * wv;
        }
        #pragma unroll
        for (int i = 0; i < 4; ++i)
            #pragma unroll
            for (int r = 0; r < 4; ++r) {
                float s = pr[i][r];
                s += __shfl_xor(s, 1, 64);
                s += __shfl_xor(s, 2, 64);
                s += __shfl_xor(s, 4, 64);
                s += __shfl_xor(s, 8, 64);
                pr[i][r] = s;
            }
        if ((lane & 15) == 0) {
            #pragma unroll
            for (int i = 0; i < 4; ++i)
                #pragma unroll
                for (int r = 0; r < 4; ++r)
                    hpart[whc * 128 + whr * 64 + i * 16 + (lane >> 4) * 4 + r] = pr[i][r];
        }
        __syncthreads();
        if (tid < 128) {
            int row = row0 + tid;
            if (row < nrows) {
                float s = hpart[tid] + hpart[128 + tid] + hpart[256 + tid]
                        + hpart[384 + tid] + bh2[0];
                outF[row] = 1.f / (1.f + expf(-s));
            }
        }
    }
}

static inline size_t align256(size_t x) { return (x + 255) & ~(size_t)255; }

extern "C" void kernel_launch(void* const* d_in, const int* in_sizes, int n_in,
                              void* d_out, int out_size, void* d_ws, size_t ws_size,
                              hipStream_t stream) {
    const float* x    = (const float*)d_in[0];
    const int* ei     = (const int*)d_in[1];
    const float* W1_l = (const float*)d_in[2];
    const float* b1_l = (const float*)d_in[3];
    const float* W1_r = (const float*)d_in[4];
    const float* W2_l = (const float*)d_in[5];
    const float* b2_l = (const float*)d_in[6];
    const float* W2_r = (const float*)d_in[7];
    const float* Wh1  = (const float*)d_in[8];
    const float* bh1  = (const float*)d_in[9];
    const float* Wh2  = (const float*)d_in[10];
    const float* bh2  = (const float*)d_in[11];
    float* out = (float*)d_out;

    const int* src = ei;
    const int* dst = ei + N_EDGES;

    const size_t SZ_N128 = (size_t)N_NODES * DIM_IN * sizeof(u16);   // 12.8 MB
    const size_t SZ_W128x256 = (size_t)128 * 256 * sizeof(u16);      // 64 KB

    char* ws = (char*)d_ws;
    size_t off_ = 0;
    auto alloc = [&](size_t bytes) { size_t o = off_; off_ += align256(bytes); return o; };

    size_t o_cnt = alloc((size_t)N_PAD * 4);
    size_t o_gcur = alloc((size_t)512 * 4);
    size_t o_csr = alloc((size_t)N_PAD * CAP * 4);           // 12.8 MB
    size_t o_bin = alloc((size_t)NBKT * BCAP * 8);           // 8 MB
    size_t o_w1l = alloc(SZ_W128x256);
    size_t o_w1r = alloc(SZ_W128x256);
    size_t o_w2l = alloc(2 * SZ_W128x256);
    size_t o_w2r = alloc(2 * SZ_W128x256);
    size_t o_wh1 = alloc(SZ_W128x256);
    size_t o_xh  = alloc(SZ_N128);
    size_t o_xf8 = alloc((size_t)N_NODES * DIM_IN);          // 6.4 MB fp8
    size_t o_a1  = alloc(SZ_N128);
    size_t o_h1  = alloc((size_t)N_PAD * DIM_H * sizeof(u16));  // padded rows
    size_t o_h1f = alloc((size_t)N_PAD * DIM_H);                // padded rows
    size_t o_a2  = alloc((size_t)N_NODES * DIM_H * sizeof(u16));
    if (ws_size < off_) return;

    int* cnt  = (int*)(ws + o_cnt);
    int* gcur = (int*)(ws + o_gcur);
    int* csr  = (int*)(ws + o_csr);
    int2* binbuf = (int2*)(ws + o_bin);
    u16* w1l_h = (u16*)(ws + o_w1l);
    u16* w1r_h = (u16*)(ws + o_w1r);
    u16* w2l_h = (u16*)(ws + o_w2l);
    u16* w2r_h = (u16*)(ws + o_w2r);
    u16* wh1_h = (u16*)(ws + o_wh1);
    u16* x_hi    = (u16*)(ws + o_xh);
    u32* x_f8    = (u32*)(ws + o_xf8);
    u16* agg1_hi = (u16*)(ws + o_a1);
    u16* h1_hi   = (u16*)(ws + o_h1);
    u8*  h1_f8   = (u8*)(ws + o_h1f);
    u16* agg2_hi = (u16*)(ws + o_a2);

    // ---- prep: gcur init + x (bf16+fp8) + weight transposes, 1 launch ----
    prep<<<2 + 6250 + 128 + 128 + 256 + 256 + 128, 256, 0, stream>>>(
        x, W1_l, W1_r, W2_l, W2_r, Wh1,
        x_hi, x_f8, w1l_h, w1r_h, w2l_h, w2r_h, wh1_h, gcur);

    // ---- two-phase binned CSR ----
    binA<<<BINA_BLOCKS, 256, 0, stream>>>(src, dst, gcur, binbuf);
    binB<<<NBKT, 256, 0, stream>>>(gcur, binbuf, cnt, csr);

    const int RB = (N_NODES + 127) / 128;   // 391 row blocks
    const int AB = (N_NODES + 3) / 4;       // 12500 aggregate blocks

    // ---- conv1: fp8 gather from x ----
    aggregate_f8<8><<<AB, 256, 0, stream>>>(
        (const uint4*)x_f8, cnt, csr, agg1_hi, N_NODES);
    gemm_fused<0><<<RB, 512, 0, stream>>>(
        agg1_hi, x_hi, w1l_h, w1r_h, b1_l,
        nullptr, nullptr, nullptr, nullptr, h1_hi, h1_f8, nullptr, N_NODES, 128);

    // ---- conv2: fp8 gather from h1 + fused risk head ----
    aggregate_f8<16><<<AB, 256, 0, stream>>>(
        (const uint4*)h1_f8, cnt, csr, agg2_hi, N_NODES);
    gemm_fused<1><<<RB, 512, 0, stream>>>(
        agg2_hi, h1_hi, w2l_h, w2r_h, b2_l,
        wh1_h, bh1, Wh2, bh2, nullptr, nullptr, out, N_NODES, 256);
}